// Round 4
// baseline (435.644 us; speedup 1.0000x reference)
//
#include <hip/hip_runtime.h>

// DotProductAttention: B=32 H=8 S=1024 D=16, fp32.
// logits = (Q·K^T)/4; logits = 10*tanh(logits); mask(k) -> -inf; softmax; out = P·V.
// Trick: logits <= 10 always, so softmax with FIXED max=10:
//   p = exp(10*tanh(x) - 10) = exp(-20 / (e^{2x} + 1)),  p in (e^-20, 1]
// -> no online max/rescale needed; masked positions contribute p = 0.

constexpr int Bv = 32, Hv = 8, Sv = 1024, Dv = 16;
constexpr int KC = 128;   // k-chunk rows staged in LDS
constexpr int QT = 256;   // q rows per block (= blockDim.x)

__global__ __launch_bounds__(256)
void attn_fwd(const float* __restrict__ Q, const float* __restrict__ K,
              const float* __restrict__ V, const int* __restrict__ mask,
              float* __restrict__ out)
{
    __shared__ float Ks[KC * Dv];   // 8 KB
    __shared__ float Vs[KC * Dv];   // 8 KB
    __shared__ float Ms[KC];        // 0.5 KB  (0.0 = masked, 1.0 = keep)

    const int tid = threadIdx.x;
    const int bh  = blockIdx.x >> 2;   // (b*H + h), 0..255
    const int qt  = blockIdx.x & 3;    // which 256-row q tile
    const int b   = bh >> 3;
    const int q   = qt * QT + tid;

    const float* Qp = Q + ((size_t)bh * Sv + q) * Dv;
    const float* Kp = K + (size_t)bh * Sv * Dv;
    const float* Vp = V + (size_t)bh * Sv * Dv;
    const int* mp = mask + (size_t)b * Sv;   // bool inputs arrive as int32

    // Q row -> registers (64B contiguous per thread, wave reads 4KB contiguous)
    float qr[Dv];
#pragma unroll
    for (int i = 0; i < 4; ++i) {
        float4 t = *(const float4*)(Qp + i * 4);
        qr[i*4+0] = t.x; qr[i*4+1] = t.y; qr[i*4+2] = t.z; qr[i*4+3] = t.w;
    }

    float acc[Dv];
#pragma unroll
    for (int i = 0; i < Dv; ++i) acc[i] = 0.f;
    float lsum = 0.f;

    for (int c = 0; c < Sv / KC; ++c) {
        __syncthreads();   // protect LDS from previous iteration's readers
        // stage K/V chunk: KC*Dv = 2048 floats = 512 float4; 256 threads x 2 each
        const float4* ksrc = (const float4*)(Kp + c * KC * Dv);
        const float4* vsrc = (const float4*)(Vp + c * KC * Dv);
        float4* kdst = (float4*)Ks;
        float4* vdst = (float4*)Vs;
#pragma unroll
        for (int i = 0; i < 2; ++i) {
            kdst[tid + i * 256] = ksrc[tid + i * 256];
            vdst[tid + i * 256] = vsrc[tid + i * 256];
        }
        if (tid < KC) Ms[tid] = mp[c * KC + tid] ? 0.f : 1.f;
        __syncthreads();

#pragma unroll 4
        for (int kk = 0; kk < KC; ++kk) {
            const float* kr = Ks + kk * Dv;   // same addr across wave -> broadcast
            float dot = 0.f;
#pragma unroll
            for (int d = 0; d < Dv; ++d) dot = fmaf(qr[d], kr[d], dot);
            // p = exp(-20 / (e^{dot/2} + 1)); e^{2x}, x = dot/4
            float e2x = __expf(dot * 0.5f);                    // v_exp_f32 path
            float r   = __builtin_amdgcn_rcpf(e2x + 1.0f);     // ~1ulp rcp
            float p   = __expf(-20.0f * r);
            p *= Ms[kk];                                       // mask -> p=0
            lsum += p;
            const float* vr = Vs + kk * Dv;
#pragma unroll
            for (int d = 0; d < Dv; ++d) acc[d] = fmaf(p, vr[d], acc[d]);
        }
    }

    const float rnorm = 1.0f / lsum;   // softmax denominator (fixed-max form)
    float* op = out + ((size_t)bh * Sv + q) * Dv;
#pragma unroll
    for (int i = 0; i < 4; ++i) {
        float4 t;
        t.x = acc[i*4+0] * rnorm; t.y = acc[i*4+1] * rnorm;
        t.z = acc[i*4+2] * rnorm; t.w = acc[i*4+3] * rnorm;
        *(float4*)(op + i * 4) = t;
    }
}

extern "C" void kernel_launch(void* const* d_in, const int* in_sizes, int n_in,
                              void* d_out, int out_size, void* d_ws, size_t ws_size,
                              hipStream_t stream)
{
    const float* Q = (const float*)d_in[0];
    const float* K = (const float*)d_in[1];
    const float* V = (const float*)d_in[2];
    const int* mask = (const int*)d_in[3];
    float* out = (float*)d_out;

    dim3 grid(Bv * Hv * (Sv / QT));   // 1024 blocks
    dim3 block(QT);
    attn_fwd<<<grid, block, 0, stream>>>(Q, K, V, mask, out);
}

// Round 5
// 379.531 us; speedup vs baseline: 1.1478x; 1.1478x over previous
//
#include <hip/hip_runtime.h>

// DotProductAttention: B=32 H=8 S=1024 D=16, fp32.
// logits = (Q·K^T)/4; 10*tanh; key-mask -> -inf; softmax; out = P·V.
// Fixed-max softmax: logits <= 10 always, so p = exp(10*tanh(x)-10)
//   = exp(-20/(e^{2x}+1)) with x = dot/4 -> no online max, masked p = 0.
// R4->R5: in-block k-split (2 threads per q-row, half the keys each) to
// raise occupancy 16 -> 32 waves/CU; merge partials via LDS (no rescale
// needed thanks to fixed max).

constexpr int Bv = 32, Hv = 8, Sv = 1024, Dv = 16;
constexpr int KC = 128;   // k-chunk rows staged in LDS
constexpr int QT = 256;   // q rows per block
constexpr int NT = 512;   // threads per block (= 2 * QT)
constexpr int KH = KC / 2; // keys per thread per chunk

__global__ __launch_bounds__(NT, 8)
void attn_fwd(const float* __restrict__ Q, const float* __restrict__ K,
              const float* __restrict__ V, const int* __restrict__ mask,
              float* __restrict__ out)
{
    __shared__ float Ks[KC * Dv];    // 8 KB
    __shared__ float Vs[KC * Dv];    // 8 KB
    __shared__ float Ms[KC];         // 0.5 KB
    __shared__ float Cb[QT][20];     // 20 KB combine buffer: acc[16] + lsum (pad->20)

    const int tid = threadIdx.x;
    const int qs  = tid & (QT - 1);    // q slot in tile
    const int h   = tid >> 8;          // k-half: 0 -> rows [0,64), 1 -> [64,128)
    const int bh  = blockIdx.x >> 2;   // b*H + h
    const int qt  = blockIdx.x & 3;
    const int b   = bh >> 3;
    const int q   = qt * QT + qs;

    const float* Qp = Q + ((size_t)bh * Sv + q) * Dv;
    const float* Kp = K + (size_t)bh * Sv * Dv;
    const float* Vp = V + (size_t)bh * Sv * Dv;
    const int*   mp = mask + (size_t)b * Sv;   // bool inputs arrive as int32

    float qr[Dv];
#pragma unroll
    for (int i = 0; i < 4; ++i) {
        float4 t = *(const float4*)(Qp + i * 4);
        qr[i*4+0] = t.x; qr[i*4+1] = t.y; qr[i*4+2] = t.z; qr[i*4+3] = t.w;
    }

    float acc[Dv];
#pragma unroll
    for (int i = 0; i < Dv; ++i) acc[i] = 0.f;
    float lsum = 0.f;

    const int base = h * KH;   // this thread's row range within each chunk

    for (int c = 0; c < Sv / KC; ++c) {
        __syncthreads();   // protect LDS from previous iteration's readers
        // stage K/V chunk: KC*Dv = 2048 floats = 512 float4; 512 threads x 1
        ((float4*)Ks)[tid] = ((const float4*)(Kp + c * KC * Dv))[tid];
        ((float4*)Vs)[tid] = ((const float4*)(Vp + c * KC * Dv))[tid];
        if (tid < KC) Ms[tid] = mp[c * KC + tid] ? 0.f : 1.f;
        __syncthreads();

#pragma unroll 4
        for (int kk = 0; kk < KH; ++kk) {
            const int r = base + kk;
            const float* kr = Ks + r * Dv;   // wave-uniform addr -> broadcast
            float dot = 0.f;
#pragma unroll
            for (int d = 0; d < Dv; ++d) dot = fmaf(qr[d], kr[d], dot);
            float e2x = __expf(dot * 0.5f);
            float rc  = __builtin_amdgcn_rcpf(e2x + 1.0f);
            float p   = __expf(-20.0f * rc);
            p *= Ms[r];
            lsum += p;
            const float* vr = Vs + r * Dv;
#pragma unroll
            for (int d = 0; d < Dv; ++d) acc[d] = fmaf(p, vr[d], acc[d]);
        }
    }

    // merge the two k-halves (fixed-max softmax: plain adds, no rescale)
    if (h == 1) {
#pragma unroll
        for (int i = 0; i < 4; ++i) {
            float4 t;
            t.x = acc[i*4+0]; t.y = acc[i*4+1]; t.z = acc[i*4+2]; t.w = acc[i*4+3];
            *(float4*)&Cb[qs][i*4] = t;
        }
        Cb[qs][16] = lsum;
    }
    __syncthreads();
    if (h == 0) {
#pragma unroll
        for (int i = 0; i < Dv; ++i) acc[i] += Cb[qs][i];
        lsum += Cb[qs][16];
        const float rnorm = 1.0f / lsum;
        float* op = out + ((size_t)bh * Sv + q) * Dv;
#pragma unroll
        for (int i = 0; i < 4; ++i) {
            float4 t;
            t.x = acc[i*4+0] * rnorm; t.y = acc[i*4+1] * rnorm;
            t.z = acc[i*4+2] * rnorm; t.w = acc[i*4+3] * rnorm;
            *(float4*)(op + i * 4) = t;
        }
    }
}

extern "C" void kernel_launch(void* const* d_in, const int* in_sizes, int n_in,
                              void* d_out, int out_size, void* d_ws, size_t ws_size,
                              hipStream_t stream)
{
    const float* Q = (const float*)d_in[0];
    const float* K = (const float*)d_in[1];
    const float* V = (const float*)d_in[2];
    const int* mask = (const int*)d_in[3];
    float* out = (float*)d_out;

    dim3 grid(Bv * Hv * (Sv / QT));   // 1024 blocks
    dim3 block(NT);
    attn_fwd<<<grid, block, 0, stream>>>(Q, K, V, mask, out);
}

// Round 7
// 265.793 us; speedup vs baseline: 1.6390x; 1.4279x over previous
//
#include <hip/hip_runtime.h>

// DotProductAttention: B=32 H=8 S=1024 D=16, fp32 in/out.
// logits = (Q·K^T)/4; 10*tanh; key-mask -> -inf; softmax; out = P·V.
// Fixed-max softmax: p = exp(10*tanh(x)-10) = exp(-20/(e^{2x}+1)), x=dot/4.
//
// MFMA structure (R6, compile-fixed R7): v_mfma_f32_16x16x16_f16, K=16=D.
// Swapped QK^T: S^T = mfma(A=K_tile, B=Q_tile) -> lane l, reg j holds
// S[k=(l>>4)*4+j][q=l&15] == P-as-A-fragment layout for the PV mfma.
// Softmax applied elementwise in-register, packed straight into PV A operand.
// No LDS, no barriers, no shuffles in the matmul chain.
// Precision: QK via fp16 hi/lo split (3 MFMAs) ~ fp32 dot; P,V plain fp16.

typedef __attribute__((ext_vector_type(4))) _Float16 half4;
typedef __attribute__((ext_vector_type(4))) float floatx4;

constexpr int Bv = 32, Hv = 8, Sv = 1024, Dv = 16;
constexpr int NS = 4;   // 16-row q-strips per wave (64 q rows/wave)

__global__ __launch_bounds__(256)
void attn_mfma(const float* __restrict__ Q, const float* __restrict__ K,
               const float* __restrict__ V, const int* __restrict__ mask,
               float* __restrict__ out)
{
    const int lane = threadIdx.x & 63;
    const int W    = blockIdx.x * 4 + (threadIdx.x >> 6);  // global wave id
    const int head = W >> 4;          // 0..255  (= b*H + h)
    const int qb   = (W & 15) * 64;   // this wave's 64-row q range
    const int bidx = head >> 3;       // batch index for mask
    const int r    = lane & 15;       // row-in-16 of fragment
    const int g    = lane >> 4;       // k-group 0..3

    const float* Qp = Q + (size_t)head * Sv * Dv;
    const float* Kp = K + (size_t)head * Sv * Dv;
    const float* Vp = V + (size_t)head * Sv * Dv;
    const int*   mp = mask + (size_t)bidx * Sv;   // bool arrives as int32

    // Q fragments (B operand: B[k=d][n=q], lane holds q=r, d=4g..4g+3),
    // hi/lo fp16 split for fp32-grade dot precision.
    half4 qh[NS], ql[NS];
#pragma unroll
    for (int s = 0; s < NS; ++s) {
        float4 t = *(const float4*)(Qp + (size_t)(qb + s*16 + r) * Dv + 4*g);
        half4 h, l;
        h.x = (_Float16)t.x; h.y = (_Float16)t.y;
        h.z = (_Float16)t.z; h.w = (_Float16)t.w;
        l.x = (_Float16)(t.x - (float)h.x); l.y = (_Float16)(t.y - (float)h.y);
        l.z = (_Float16)(t.z - (float)h.z); l.w = (_Float16)(t.w - (float)h.w);
        qh[s] = h; ql[s] = l;
    }

    floatx4 acc[NS];
    float lsum[NS];
#pragma unroll
    for (int s = 0; s < NS; ++s) { acc[s] = (floatx4)(0.f); lsum[s] = 0.f; }

    const float C1 = 0.72134752044448170f;    // 0.5 * log2(e)
    const float C2 = -28.853900817779268f;    // -20 * log2(e)

    for (int kt = 0; kt < Sv / 16; ++kt) {
        // K fragment (A operand: A[m=k_row][k=d], lane holds k_row=r, d=4g..4g+3)
        float4 kv = *(const float4*)(Kp + (size_t)(kt*16 + r) * Dv + 4*g);
        half4 kh, kl;
        kh.x = (_Float16)kv.x; kh.y = (_Float16)kv.y;
        kh.z = (_Float16)kv.z; kh.w = (_Float16)kv.w;
        kl.x = (_Float16)(kv.x - (float)kh.x); kl.y = (_Float16)(kv.y - (float)kh.y);
        kl.z = (_Float16)(kv.z - (float)kh.z); kl.w = (_Float16)(kv.w - (float)kh.w);

        // V fragment (B operand of PV: B[k][n=d], lane holds d=r, k=4g+j)
        const int krow = kt*16 + 4*g;
        half4 vf;
        vf.x = (_Float16)Vp[(size_t)(krow+0)*Dv + r];
        vf.y = (_Float16)Vp[(size_t)(krow+1)*Dv + r];
        vf.z = (_Float16)Vp[(size_t)(krow+2)*Dv + r];
        vf.w = (_Float16)Vp[(size_t)(krow+3)*Dv + r];

        // mask for this lane's 4 k rows
        int4 mv = *(const int4*)(mp + krow);

#pragma unroll
        for (int s = 0; s < NS; ++s) {
            // S^T tile: st[j] = dot(K[kt*16+4g+j], Q[qb+s*16+r])  (fp32-grade)
            floatx4 st = __builtin_amdgcn_mfma_f32_16x16x16f16(kh, qh[s], (floatx4)(0.f), 0, 0, 0);
            st = __builtin_amdgcn_mfma_f32_16x16x16f16(kh, ql[s], st, 0, 0, 0);
            st = __builtin_amdgcn_mfma_f32_16x16x16f16(kl, qh[s], st, 0, 0, 0);

            // fixed-max softmax numerator, elementwise in-register
            float p0 = exp2f(C2 * __builtin_amdgcn_rcpf(exp2f(C1 * st.x) + 1.f));
            float p1 = exp2f(C2 * __builtin_amdgcn_rcpf(exp2f(C1 * st.y) + 1.f));
            float p2 = exp2f(C2 * __builtin_amdgcn_rcpf(exp2f(C1 * st.z) + 1.f));
            float p3 = exp2f(C2 * __builtin_amdgcn_rcpf(exp2f(C1 * st.w) + 1.f));
            p0 = mv.x ? 0.f : p0;
            p1 = mv.y ? 0.f : p1;
            p2 = mv.z ? 0.f : p2;
            p3 = mv.w ? 0.f : p3;
            lsum[s] += (p0 + p1) + (p2 + p3);

            // pack P -> fp16 A-fragment (layout already matches)
            half4 pf;
            pf.x = (_Float16)p0; pf.y = (_Float16)p1;
            pf.z = (_Float16)p2; pf.w = (_Float16)p3;

            acc[s] = __builtin_amdgcn_mfma_f32_16x16x16f16(pf, vf, acc[s], 0, 0, 0);
        }
    }

    // normalize + store. acc layout: lane l, reg j -> O[qb+s*16+4g+j][d=r]
#pragma unroll
    for (int s = 0; s < NS; ++s) {
        float ls = lsum[s];
        ls += __shfl_xor(ls, 16);
        ls += __shfl_xor(ls, 32);          // all lanes: lsum for q-row = r
        float rn = __builtin_amdgcn_rcpf(ls);
        int ri = __float_as_int(rn);
        // need rnorm for q-row 4g+j -> fetch from lane (4g+j), which has r==4g+j
        float rn0 = __int_as_float(__builtin_amdgcn_ds_bpermute((4*g+0)*4, ri));
        float rn1 = __int_as_float(__builtin_amdgcn_ds_bpermute((4*g+1)*4, ri));
        float rn2 = __int_as_float(__builtin_amdgcn_ds_bpermute((4*g+2)*4, ri));
        float rn3 = __int_as_float(__builtin_amdgcn_ds_bpermute((4*g+3)*4, ri));
        float* op = out + (size_t)head * Sv * Dv + (size_t)(qb + s*16) * Dv;
        op[(4*g+0)*Dv + r] = acc[s].x * rn0;
        op[(4*g+1)*Dv + r] = acc[s].y * rn1;
        op[(4*g+2)*Dv + r] = acc[s].z * rn2;
        op[(4*g+3)*Dv + r] = acc[s].w * rn3;
    }
}

extern "C" void kernel_launch(void* const* d_in, const int* in_sizes, int n_in,
                              void* d_out, int out_size, void* d_ws, size_t ws_size,
                              hipStream_t stream)
{
    const float* Q = (const float*)d_in[0];
    const float* K = (const float*)d_in[1];
    const float* V = (const float*)d_in[2];
    const int* mask = (const int*)d_in[3];
    float* out = (float*)d_out;

    // 256 heads x 16 waves, 4 waves per 256-thread block
    dim3 grid(Bv * Hv * 16 / 4);   // 1024 blocks
    dim3 block(256);
    attn_mfma<<<grid, block, 0, stream>>>(Q, K, V, mask, out);
}

// Round 8
// 206.614 us; speedup vs baseline: 2.1085x; 1.2864x over previous
//
#include <hip/hip_runtime.h>

// DotProductAttention: B=32 H=8 S=1024 D=16, fp32 in/out.
// logits = (Q·K^T)/4; 10*tanh; key-mask -> -inf; softmax; out = P·V.
// Fixed-max softmax: p = exp(10*tanh(x)-10) = exp(-20/(e^{2x}+1)), x=dot/4.
// In exp2 domain with C1=0.5*log2e folded into Q: t = C1*dot from MFMA,
//   p = exp2(C2 * rcp(exp2(t) + 1)),  C2 = -20*log2e.
//
// R7->R8: VALU-bound at 89.6% busy, MfmaUtil 13.7 -> cut softmax VALU:
//  - __builtin_amdgcn_exp2f: single v_exp_f32 (exp2f lowers to a multi-inst
//    denormal-safe expansion without fast-math)
//  - C1 scale folded into Q fragments at load (hi/lo split after scaling)
//  - mask folded into QK MFMA C-operand as -1e4 bias (4 cndmask/ktile,
//    replaces 16 per-element cndmasks; masked p=2^-28.8=2e-9 -> 0 in fp16)
//  - cvt_pkrtz for P->fp16 pack (2 inst / 4 elems)

typedef __attribute__((ext_vector_type(4))) _Float16 half4;
typedef __attribute__((ext_vector_type(2))) __fp16   fp16x2;
typedef __attribute__((ext_vector_type(4))) float    floatx4;

constexpr int Bv = 32, Hv = 8, Sv = 1024, Dv = 16;
constexpr int NS = 4;   // 16-row q-strips per wave (64 q rows/wave)

__global__ __launch_bounds__(256)
void attn_mfma(const float* __restrict__ Q, const float* __restrict__ K,
               const float* __restrict__ V, const int* __restrict__ mask,
               float* __restrict__ out)
{
    const int lane = threadIdx.x & 63;
    const int W    = blockIdx.x * 4 + (threadIdx.x >> 6);  // global wave id
    const int head = W >> 4;          // 0..255  (= b*H + h)
    const int qb   = (W & 15) * 64;   // this wave's 64-row q range
    const int bidx = head >> 3;       // batch index for mask
    const int r    = lane & 15;       // row-in-16 of fragment
    const int g    = lane >> 4;       // k-group 0..3

    const float* Qp = Q + (size_t)head * Sv * Dv;
    const float* Kp = K + (size_t)head * Sv * Dv;
    const float* Vp = V + (size_t)head * Sv * Dv;
    const int*   mp = mask + (size_t)bidx * Sv;   // bool arrives as int32

    const float C1 = 0.72134752044448170f;    // 0.5 * log2(e)  (folded into Q)
    const float C2 = -28.853900817779268f;    // -20 * log2(e)

    // Q fragments (B operand: lane holds q=r, d=4g..4g+3), scaled by C1,
    // then hi/lo fp16 split for fp32-grade dot precision.
    half4 qh[NS], ql[NS];
#pragma unroll
    for (int s = 0; s < NS; ++s) {
        float4 t = *(const float4*)(Qp + (size_t)(qb + s*16 + r) * Dv + 4*g);
        t.x *= C1; t.y *= C1; t.z *= C1; t.w *= C1;
        half4 h, l;
        h.x = (_Float16)t.x; h.y = (_Float16)t.y;
        h.z = (_Float16)t.z; h.w = (_Float16)t.w;
        l.x = (_Float16)(t.x - (float)h.x); l.y = (_Float16)(t.y - (float)h.y);
        l.z = (_Float16)(t.z - (float)h.z); l.w = (_Float16)(t.w - (float)h.w);
        qh[s] = h; ql[s] = l;
    }

    floatx4 acc[NS];
    float lsum[NS];
#pragma unroll
    for (int s = 0; s < NS; ++s) { acc[s] = (floatx4)(0.f); lsum[s] = 0.f; }

    for (int kt = 0; kt < Sv / 16; ++kt) {
        // K fragment (A operand: lane holds k_row=r, d=4g..4g+3), hi/lo split
        float4 kv = *(const float4*)(Kp + (size_t)(kt*16 + r) * Dv + 4*g);
        half4 kh, kl;
        kh.x = (_Float16)kv.x; kh.y = (_Float16)kv.y;
        kh.z = (_Float16)kv.z; kh.w = (_Float16)kv.w;
        kl.x = (_Float16)(kv.x - (float)kh.x); kl.y = (_Float16)(kv.y - (float)kh.y);
        kl.z = (_Float16)(kv.z - (float)kh.z); kl.w = (_Float16)(kv.w - (float)kh.w);

        // V fragment (B operand of PV: lane holds d=r, k rows 4g..4g+3)
        const int krow = kt*16 + 4*g;
        half4 vf;
        vf.x = (_Float16)Vp[(size_t)(krow+0)*Dv + r];
        vf.y = (_Float16)Vp[(size_t)(krow+1)*Dv + r];
        vf.z = (_Float16)Vp[(size_t)(krow+2)*Dv + r];
        vf.w = (_Float16)Vp[(size_t)(krow+3)*Dv + r];

        // mask -> additive bias in QK accumulator (C-operand layout = S^T)
        int4 mv = *(const int4*)(mp + krow);
        floatx4 bias;
        bias.x = mv.x ? -1.0e4f : 0.f;
        bias.y = mv.y ? -1.0e4f : 0.f;
        bias.z = mv.z ? -1.0e4f : 0.f;
        bias.w = mv.w ? -1.0e4f : 0.f;

#pragma unroll
        for (int s = 0; s < NS; ++s) {
            // S^T tile (pre-scaled by C1): st[j] = C1*dot + bias
            floatx4 st = __builtin_amdgcn_mfma_f32_16x16x16f16(kh, qh[s], bias, 0, 0, 0);
            st = __builtin_amdgcn_mfma_f32_16x16x16f16(kh, ql[s], st, 0, 0, 0);
            st = __builtin_amdgcn_mfma_f32_16x16x16f16(kl, qh[s], st, 0, 0, 0);

            // p = exp2(C2 * rcp(exp2(t)+1)) — 3 trans + 2 VALU per element
            float p0 = __builtin_amdgcn_exp2f(C2 * __builtin_amdgcn_rcpf(__builtin_amdgcn_exp2f(st.x) + 1.f));
            float p1 = __builtin_amdgcn_exp2f(C2 * __builtin_amdgcn_rcpf(__builtin_amdgcn_exp2f(st.y) + 1.f));
            float p2 = __builtin_amdgcn_exp2f(C2 * __builtin_amdgcn_rcpf(__builtin_amdgcn_exp2f(st.z) + 1.f));
            float p3 = __builtin_amdgcn_exp2f(C2 * __builtin_amdgcn_rcpf(__builtin_amdgcn_exp2f(st.w) + 1.f));
            lsum[s] += (p0 + p1) + (p2 + p3);

            // pack P -> fp16 A-fragment (layout already matches)
            union { fp16x2 h2[2]; half4 h4; } u;
            u.h2[0] = __builtin_amdgcn_cvt_pkrtz(p0, p1);
            u.h2[1] = __builtin_amdgcn_cvt_pkrtz(p2, p3);

            acc[s] = __builtin_amdgcn_mfma_f32_16x16x16f16(u.h4, vf, acc[s], 0, 0, 0);
        }
    }

    // normalize + store. acc layout: lane l, reg j -> O[qb+s*16+4g+j][d=r]
#pragma unroll
    for (int s = 0; s < NS; ++s) {
        float ls = lsum[s];
        ls += __shfl_xor(ls, 16);
        ls += __shfl_xor(ls, 32);          // all lanes: lsum for q-row = r
        float rn = 1.0f / ls;              // full-precision reciprocal
        int ri = __float_as_int(rn);
        // rnorm for q-row 4g+j lives in lane (4g+j) (which has r==4g+j)
        float rn0 = __int_as_float(__builtin_amdgcn_ds_bpermute((4*g+0)*4, ri));
        float rn1 = __int_as_float(__builtin_amdgcn_ds_bpermute((4*g+1)*4, ri));
        float rn2 = __int_as_float(__builtin_amdgcn_ds_bpermute((4*g+2)*4, ri));
        float rn3 = __int_as_float(__builtin_amdgcn_ds_bpermute((4*g+3)*4, ri));
        float* op = out + (size_t)head * Sv * Dv + (size_t)(qb + s*16) * Dv;
        op[(4*g+0)*Dv + r] = acc[s].x * rn0;
        op[(4*g+1)*Dv + r] = acc[s].y * rn1;
        op[(4*g+2)*Dv + r] = acc[s].z * rn2;
        op[(4*g+3)*Dv + r] = acc[s].w * rn3;
    }
}

extern "C" void kernel_launch(void* const* d_in, const int* in_sizes, int n_in,
                              void* d_out, int out_size, void* d_ws, size_t ws_size,
                              hipStream_t stream)
{
    const float* Q = (const float*)d_in[0];
    const float* K = (const float*)d_in[1];
    const float* V = (const float*)d_in[2];
    const int* mask = (const int*)d_in[3];
    float* out = (float*)d_out;

    // 256 heads x 16 waves, 4 waves per 256-thread block
    dim3 grid(Bv * Hv * 16 / 4);   // 1024 blocks
    dim3 block(256);
    attn_mfma<<<grid, block, 0, stream>>>(Q, K, V, mask, out);
}

// Round 9
// 164.067 us; speedup vs baseline: 2.6553x; 1.2593x over previous
//
#include <hip/hip_runtime.h>

// DotProductAttention: B=32 H=8 S=1024 D=16, fp32 in/out.
// logits = (Q·K^T)/4; 10*tanh; key-mask -> -inf; softmax; out = P·V.
// Fixed-max softmax in exp2 domain (C1=0.5*log2e folded into Q):
//   p = exp2(C2 * rcp(exp2(t) + 1)), t = C1*dot, C2 = -20*log2e.
//
// R8->R9: trans-pipe-bound (~768 of ~950 cy/k-tile are v_exp/v_rcp at
// ~16cy each). Mask is ~50% dense -> compact keys per batch (index list
// in d_ws, built by a ballot/prefix-scan pre-kernel) and loop only over
// unmasked keys: halves trans, MFMA and K/V fetch. Tail slots (count
// rounded up to 16) get -1e4 bias -> p ~= 2e-9 ~= 0.

typedef __attribute__((ext_vector_type(4))) _Float16 half4;
typedef __attribute__((ext_vector_type(2))) __fp16   fp16x2;
typedef __attribute__((ext_vector_type(4))) float    floatx4;

constexpr int Bv = 32, Hv = 8, Sv = 1024, Dv = 16;
constexpr int NS = 4;              // 16-row q-strips per wave (64 q rows/wave)
constexpr int IDX_STRIDE = 1040;   // per-batch idx ints (1024 + 16 pad), 16B-aligned

// ---- kernel 1: per-batch key compaction ----
__global__ __launch_bounds__(1024)
void compact_mask(const int* __restrict__ mask, int* __restrict__ idx,
                  int* __restrict__ count)
{
    __shared__ int wpre[16];
    const int b = blockIdx.x;
    const int t = threadIdx.x;
    const int wid = t >> 6, lane = t & 63;
    const int keep = mask[b * Sv + t] ? 0 : 1;
    unsigned long long bal = __ballot(keep);
    const int pre  = __builtin_popcountll(bal & ((1ull << lane) - 1ull));
    const int wtot = __builtin_popcountll(bal);
    if (lane == 0) wpre[wid] = wtot;
    __syncthreads();
    if (t == 0) {
        int run = 0;
#pragma unroll
        for (int w = 0; w < 16; ++w) { int v = wpre[w]; wpre[w] = run; run += v; }
        count[b] = run;
        const int padded = (run + 15) & ~15;
        for (int i = run; i < padded; ++i) idx[b * IDX_STRIDE + i] = 0;
    }
    __syncthreads();
    if (keep) idx[b * IDX_STRIDE + wpre[wid] + pre] = t;
}

// ---- kernel 2: attention over compacted keys ----
__global__ __launch_bounds__(256)
void attn_mfma(const float* __restrict__ Q, const float* __restrict__ K,
               const float* __restrict__ V, const int* __restrict__ idx,
               const int* __restrict__ count, float* __restrict__ out)
{
    const int lane = threadIdx.x & 63;
    const int W    = blockIdx.x * 4 + (threadIdx.x >> 6);  // global wave id
    const int head = W >> 4;          // 0..255  (= b*H + h); block-uniform
    const int qb   = (W & 15) * 64;   // this wave's 64-row q range
    const int bidx = head >> 3;       // batch index
    const int r    = lane & 15;       // row-in-16 of fragment
    const int g    = lane >> 4;       // k-group 0..3

    const float* Qp = Q + (size_t)head * Sv * Dv;
    const float* Kp = K + (size_t)head * Sv * Dv;
    const float* Vp = V + (size_t)head * Sv * Dv;
    const int*   ip = idx + (size_t)bidx * IDX_STRIDE;
    const int    cnt = count[bidx];
    const int    nkt = (cnt + 15) >> 4;

    const float C1 = 0.72134752044448170f;    // 0.5 * log2(e)  (folded into Q)
    const float C2 = -28.853900817779268f;    // -20 * log2(e)

    // Q fragments (B operand: lane holds q=r, d=4g..4g+3), scaled by C1,
    // then hi/lo fp16 split for fp32-grade dot precision.
    half4 qh[NS], ql[NS];
#pragma unroll
    for (int s = 0; s < NS; ++s) {
        float4 t = *(const float4*)(Qp + (size_t)(qb + s*16 + r) * Dv + 4*g);
        t.x *= C1; t.y *= C1; t.z *= C1; t.w *= C1;
        half4 h, l;
        h.x = (_Float16)t.x; h.y = (_Float16)t.y;
        h.z = (_Float16)t.z; h.w = (_Float16)t.w;
        l.x = (_Float16)(t.x - (float)h.x); l.y = (_Float16)(t.y - (float)h.y);
        l.z = (_Float16)(t.z - (float)h.z); l.w = (_Float16)(t.w - (float)h.w);
        qh[s] = h; ql[s] = l;
    }

    floatx4 acc[NS];
    float lsum[NS];
#pragma unroll
    for (int s = 0; s < NS; ++s) { acc[s] = (floatx4)(0.f); lsum[s] = 0.f; }

    for (int kt = 0; kt < nkt; ++kt) {
        // K fragment via gathered row index (lane holds k_row=r, d=4g..4g+3)
        const int kidx = ip[kt*16 + r];
        float4 kv = *(const float4*)(Kp + (size_t)kidx * Dv + 4*g);
        half4 kh, kl;
        kh.x = (_Float16)kv.x; kh.y = (_Float16)kv.y;
        kh.z = (_Float16)kv.z; kh.w = (_Float16)kv.w;
        kl.x = (_Float16)(kv.x - (float)kh.x); kl.y = (_Float16)(kv.y - (float)kh.y);
        kl.z = (_Float16)(kv.z - (float)kh.z); kl.w = (_Float16)(kv.w - (float)kh.w);

        // V fragment via gathered indices (lane holds d=r, k slots 4g..4g+3)
        const int slot4 = kt*16 + 4*g;
        int4 vi = *(const int4*)(ip + slot4);
        half4 vf;
        vf.x = (_Float16)Vp[(size_t)vi.x * Dv + r];
        vf.y = (_Float16)Vp[(size_t)vi.y * Dv + r];
        vf.z = (_Float16)Vp[(size_t)vi.z * Dv + r];
        vf.w = (_Float16)Vp[(size_t)vi.w * Dv + r];

        // tail-pad bias: slots >= cnt get -1e4 -> p ~= 2^-28.8 ~ 0
        floatx4 bias;
        bias.x = (slot4 + 0 < cnt) ? 0.f : -1.0e4f;
        bias.y = (slot4 + 1 < cnt) ? 0.f : -1.0e4f;
        bias.z = (slot4 + 2 < cnt) ? 0.f : -1.0e4f;
        bias.w = (slot4 + 3 < cnt) ? 0.f : -1.0e4f;

#pragma unroll
        for (int s = 0; s < NS; ++s) {
            // S^T tile (pre-scaled by C1): st[j] = C1*dot + bias
            floatx4 st = __builtin_amdgcn_mfma_f32_16x16x16f16(kh, qh[s], bias, 0, 0, 0);
            st = __builtin_amdgcn_mfma_f32_16x16x16f16(kh, ql[s], st, 0, 0, 0);
            st = __builtin_amdgcn_mfma_f32_16x16x16f16(kl, qh[s], st, 0, 0, 0);

            // p = exp2(C2 * rcp(exp2(t)+1)) — 3 trans + 2 VALU per element
            float p0 = __builtin_amdgcn_exp2f(C2 * __builtin_amdgcn_rcpf(__builtin_amdgcn_exp2f(st.x) + 1.f));
            float p1 = __builtin_amdgcn_exp2f(C2 * __builtin_amdgcn_rcpf(__builtin_amdgcn_exp2f(st.y) + 1.f));
            float p2 = __builtin_amdgcn_exp2f(C2 * __builtin_amdgcn_rcpf(__builtin_amdgcn_exp2f(st.z) + 1.f));
            float p3 = __builtin_amdgcn_exp2f(C2 * __builtin_amdgcn_rcpf(__builtin_amdgcn_exp2f(st.w) + 1.f));
            lsum[s] += (p0 + p1) + (p2 + p3);

            // pack P -> fp16 A-fragment (layout already matches)
            union { fp16x2 h2[2]; half4 h4; } u;
            u.h2[0] = __builtin_amdgcn_cvt_pkrtz(p0, p1);
            u.h2[1] = __builtin_amdgcn_cvt_pkrtz(p2, p3);

            acc[s] = __builtin_amdgcn_mfma_f32_16x16x16f16(u.h4, vf, acc[s], 0, 0, 0);
        }
    }

    // normalize + store. acc layout: lane l, reg j -> O[qb+s*16+4g+j][d=r]
#pragma unroll
    for (int s = 0; s < NS; ++s) {
        float ls = lsum[s];
        ls += __shfl_xor(ls, 16);
        ls += __shfl_xor(ls, 32);          // all lanes: lsum for q-row = r
        float rn = 1.0f / ls;
        int ri = __float_as_int(rn);
        // rnorm for q-row 4g+j lives in lane (4g+j) (which has r==4g+j)
        float rn0 = __int_as_float(__builtin_amdgcn_ds_bpermute((4*g+0)*4, ri));
        float rn1 = __int_as_float(__builtin_amdgcn_ds_bpermute((4*g+1)*4, ri));
        float rn2 = __int_as_float(__builtin_amdgcn_ds_bpermute((4*g+2)*4, ri));
        float rn3 = __int_as_float(__builtin_amdgcn_ds_bpermute((4*g+3)*4, ri));
        float* op = out + (size_t)head * Sv * Dv + (size_t)(qb + s*16) * Dv;
        op[(4*g+0)*Dv + r] = acc[s].x * rn0;
        op[(4*g+1)*Dv + r] = acc[s].y * rn1;
        op[(4*g+2)*Dv + r] = acc[s].z * rn2;
        op[(4*g+3)*Dv + r] = acc[s].w * rn3;
    }
}

extern "C" void kernel_launch(void* const* d_in, const int* in_sizes, int n_in,
                              void* d_out, int out_size, void* d_ws, size_t ws_size,
                              hipStream_t stream)
{
    const float* Q = (const float*)d_in[0];
    const float* K = (const float*)d_in[1];
    const float* V = (const float*)d_in[2];
    const int* mask = (const int*)d_in[3];
    float* out = (float*)d_out;

    // ws layout: [0,128): count[32]; [256, 256+32*1040*4): idx lists
    int* count = (int*)d_ws;
    int* idx   = (int*)((char*)d_ws + 256);

    compact_mask<<<dim3(Bv), dim3(1024), 0, stream>>>(mask, idx, count);

    // 256 heads x 16 waves, 4 waves per 256-thread block
    dim3 grid(Bv * Hv * 16 / 4);   // 1024 blocks
    dim3 block(256);
    attn_mfma<<<grid, block, 0, stream>>>(Q, K, V, idx, count, out);
}